// Round 3
// baseline (511.196 us; speedup 1.0000x reference)
//
#include <hip/hip_runtime.h>

#define SL     32768   // S*L
#define S_DIM  128
#define L_DIM  256
#define D_DIM  128
#define H_DIM  4
#define C_DIM  32
#define EPS_LN 1e-5f

// ---------------------------------------------------------------------------
// K1/K4: QKV projection  qkv[o,s,l] = sum_d w[o,d]*in[d,s,l] + b[o]
// ---------------------------------------------------------------------------
__global__ __launch_bounds__(256) void qkv_kernel(const float* __restrict__ in,
                                                  const float* __restrict__ w,
                                                  const float* __restrict__ b,
                                                  float* __restrict__ qkv) {
    __shared__ float xt[128][64];
    const int bid = blockIdx.x;
    const int s  = bid >> 2;
    const int l0 = (bid & 3) * 64;
    const int tid = threadIdx.x;

    for (int idx = tid; idx < 128 * 64; idx += 256) {
        const int d = idx >> 6, l = idx & 63;
        xt[d][l] = in[d * SL + s * L_DIM + l0 + l];
    }
    __syncthreads();

    const int lp  = tid & 31;
    const int grp = tid >> 5;
    const int o0  = grp * 48;
    const float2* xt2 = (const float2*)&xt[0][0];

    for (int ob = 0; ob < 48; ob += 4) {
        const int o = o0 + ob;
        float2 acc[4];
        #pragma unroll
        for (int io = 0; io < 4; ++io) { acc[io].x = b[o + io]; acc[io].y = b[o + io]; }
        #pragma unroll 4
        for (int d = 0; d < 128; ++d) {
            const float2 xv = xt2[d * 32 + lp];
            #pragma unroll
            for (int io = 0; io < 4; ++io) {
                const float wv = w[(o + io) * 128 + d];
                acc[io].x += wv * xv.x;
                acc[io].y += wv * xv.y;
            }
        }
        #pragma unroll
        for (int io = 0; io < 4; ++io) {
            *(float2*)&qkv[(o + io) * SL + s * L_DIM + l0 + lp * 2] = acc[io];
        }
    }
}

// ---------------------------------------------------------------------------
// K2: row attention v2. grid 512 (h,s), block 512: jh = tid>>8 (j-half),
// i = tid&255 (query). LDS tiles transposed to [j][c] (pad 36) so inner-loop
// K/V reads are float4 BROADCASTS. No-max softmax (scores |.|<~2, fp32-safe)
// -> no divergence, no rescale. Halves merge partial (o, lsum) via LDS.
// ---------------------------------------------------------------------------
#define RJT 32
__global__ __launch_bounds__(512) void row_attn_kernel(const float* __restrict__ qkv,
                                                       float* __restrict__ ao) {
    __shared__ float kt[2][RJT][36];
    __shared__ float vt[2][RJT][36];
    __shared__ float mrg[256][17];
    const int h = blockIdx.x >> 7;
    const int s = blockIdx.x & 127;
    const int tid = threadIdx.x;
    const int jh  = tid >> 8;
    const int i   = tid & 255;

    const float* kbase = qkv + (128 + h * 32) * SL + s * L_DIM;
    const float* vbase = qkv + (256 + h * 32) * SL + s * L_DIM;

    float qr[32];
    const float* qbase = qkv + (h * 32) * SL + s * L_DIM + i;
    #pragma unroll
    for (int c = 0; c < 32; ++c) qr[c] = qbase[c * SL];

    float lsum = 0.f;
    float o[32];
    #pragma unroll
    for (int d = 0; d < 32; ++d) o[d] = 0.f;

    for (int j0 = 0; j0 < 128; j0 += RJT) {
        __syncthreads();
        // load K,V tiles for both halves, transposing to [j][c]
        for (int idx = tid; idx < 1024; idx += 512) {
            const int t   = idx >> 9;
            const int hf  = (idx >> 8) & 1;
            const int rem = idx & 255;
            const int c   = rem >> 3;
            const int j4  = (rem & 7) * 4;
            const float4 v4 = *(const float4*)((t ? vbase : kbase) + c * SL + hf * 128 + j0 + j4);
            float (*dst)[36] = t ? vt[hf] : kt[hf];
            dst[j4 + 0][c] = v4.x;
            dst[j4 + 1][c] = v4.y;
            dst[j4 + 2][c] = v4.z;
            dst[j4 + 3][c] = v4.w;
        }
        __syncthreads();
        #pragma unroll 2
        for (int jj = 0; jj < RJT; ++jj) {
            const float4* krow = (const float4*)kt[jh][jj];
            float sc = 0.f;
            #pragma unroll
            for (int c4 = 0; c4 < 8; ++c4) {
                const float4 kk = krow[c4];
                sc += qr[c4*4+0]*kk.x + qr[c4*4+1]*kk.y + qr[c4*4+2]*kk.z + qr[c4*4+3]*kk.w;
            }
            const float p = __expf(sc);
            lsum += p;
            const float4* vrow = (const float4*)vt[jh][jj];
            #pragma unroll
            for (int d4 = 0; d4 < 8; ++d4) {
                const float4 vv = vrow[d4];
                o[d4*4+0] += p * vv.x;
                o[d4*4+1] += p * vv.y;
                o[d4*4+2] += p * vv.z;
                o[d4*4+3] += p * vv.w;
            }
        }
    }
    // merge halves (no-max partials add directly)
    __syncthreads();
    if (jh == 1) {
        #pragma unroll
        for (int k = 0; k < 16; ++k) mrg[i][k] = o[k];
        mrg[i][16] = lsum;
    }
    __syncthreads();
    if (jh == 0) {
        #pragma unroll
        for (int k = 0; k < 16; ++k) o[k] += mrg[i][k];
        lsum += mrg[i][16];
    }
    __syncthreads();
    if (jh == 1) {
        #pragma unroll
        for (int k = 0; k < 16; ++k) mrg[i][k] = o[16 + k];
    }
    __syncthreads();
    if (jh == 0) {
        #pragma unroll
        for (int k = 0; k < 16; ++k) o[16 + k] += mrg[i][k];
        const float inv = 1.f / lsum;
        float* obase = ao + (h * 32) * SL + s * L_DIM + i;
        #pragma unroll
        for (int d = 0; d < 32; ++d) obase[d * SL] = o[d] * inv;
    }
}

// ---------------------------------------------------------------------------
// K5: column attention. grid 512: h(4) x i-tile(16) x l-tile(8). block 256.
// No-max softmax (removes divergent rescale).
// ---------------------------------------------------------------------------
#define CJT 8
__global__ __launch_bounds__(256) void col_attn_kernel(const float* __restrict__ qkv,
                                                       float* __restrict__ ao) {
    __shared__ float kt[32][CJT][32];
    __shared__ float vt[32][CJT][32];
    const int bid = blockIdx.x;
    const int h  = bid >> 7;
    const int i0 = ((bid >> 3) & 15) * 8;
    const int l0 = (bid & 7) * 32;
    const int tid = threadIdx.x;
    const int myl = tid & 31;
    const int ii  = tid >> 5;
    const int i = i0 + ii;
    const int l = l0 + myl;

    float qr[32];
    const float* qbase = qkv + (h * 32) * SL + i * L_DIM + l;
    #pragma unroll
    for (int c = 0; c < 32; ++c) qr[c] = qbase[c * SL];

    const float* kbase = qkv + (128 + h * 32) * SL + l0;
    const float* vbase = qkv + (256 + h * 32) * SL + l0;

    float lsum = 0.f;
    float o[32];
    #pragma unroll
    for (int d = 0; d < 32; ++d) o[d] = 0.f;

    for (int j0 = 0; j0 < 128; j0 += CJT) {
        __syncthreads();
        for (int idx = tid; idx < 32 * CJT * 8; idx += 256) {
            const int c   = idx >> 6;
            const int rem = idx & 63;
            const int jj  = rem >> 3;
            const int l4  = rem & 7;
            *(float4*)&kt[c][jj][l4 * 4] =
                *(const float4*)&kbase[c * SL + (j0 + jj) * L_DIM + l4 * 4];
            *(float4*)&vt[c][jj][l4 * 4] =
                *(const float4*)&vbase[c * SL + (j0 + jj) * L_DIM + l4 * 4];
        }
        __syncthreads();
        #pragma unroll
        for (int jj = 0; jj < CJT; ++jj) {
            float sc = 0.f;
            #pragma unroll
            for (int c = 0; c < 32; ++c) sc += qr[c] * kt[c][jj][myl];
            const float p = __expf(sc);
            lsum += p;
            #pragma unroll
            for (int d = 0; d < 32; ++d) o[d] += p * vt[d][jj][myl];
        }
    }
    const float inv = 1.f / lsum;
    float* obase = ao + (h * 32) * SL + i * L_DIM + l;
    #pragma unroll
    for (int d = 0; d < 32; ++d) obase[d * SL] = o[d] * inv;
}

// ---------------------------------------------------------------------------
// K3/K6: channel LayerNorm with residual: out = LN(a + r) * gamma + beta
// grid 256 x block 128 so all 256 CUs get work.
// ---------------------------------------------------------------------------
__global__ __launch_bounds__(128) void ln_kernel(const float* __restrict__ a,
                                                 const float* __restrict__ r,
                                                 const float* __restrict__ gamma,
                                                 const float* __restrict__ beta,
                                                 float* __restrict__ out) {
    const int pos = blockIdx.x * 128 + threadIdx.x;
    float sum = 0.f, sumsq = 0.f;
    #pragma unroll 8
    for (int d = 0; d < 128; ++d) {
        const float v = a[d * SL + pos] + r[d * SL + pos];
        sum += v;
        sumsq += v * v;
    }
    const float mean = sum * (1.f / 128.f);
    const float var  = sumsq * (1.f / 128.f) - mean * mean;
    const float rstd = rsqrtf(var + EPS_LN);
    #pragma unroll 8
    for (int d = 0; d < 128; ++d) {
        const float v = a[d * SL + pos] + r[d * SL + pos];
        out[d * SL + pos] = (v - mean) * rstd * gamma[d] + beta[d];
    }
}

// ---------------------------------------------------------------------------
extern "C" void kernel_launch(void* const* d_in, const int* in_sizes, int n_in,
                              void* d_out, int out_size, void* d_ws, size_t ws_size,
                              hipStream_t stream) {
    const float* x     = (const float*)d_in[0];
    const float* w_row = (const float*)d_in[1];
    const float* b_row = (const float*)d_in[2];
    const float* w_col = (const float*)d_in[3];
    const float* b_col = (const float*)d_in[4];
    const float* g1    = (const float*)d_in[5];
    const float* be1   = (const float*)d_in[6];
    const float* g2    = (const float*)d_in[7];
    const float* be2   = (const float*)d_in[8];
    float* out = (float*)d_out;

    float* qkv  = (float*)d_ws;
    float* ao   = qkv + 384 * SL;
    float* out1 = ao + 128 * SL;

    qkv_kernel<<<512, 256, 0, stream>>>(x, w_row, b_row, qkv);
    row_attn_kernel<<<512, 512, 0, stream>>>(qkv, ao);
    ln_kernel<<<256, 128, 0, stream>>>(x, ao, g1, be1, out1);
    qkv_kernel<<<512, 256, 0, stream>>>(out1, w_col, b_col, qkv);
    col_attn_kernel<<<512, 256, 0, stream>>>(qkv, ao);
    ln_kernel<<<256, 128, 0, stream>>>(out1, ao, g2, be2, out);
}

// Round 4
// 163.634 us; speedup vs baseline: 3.1240x; 3.1240x over previous
//
#include <hip/hip_runtime.h>
#include <hip/hip_bf16.h>

#define SL     32768
#define EPS_LN 1e-5f

typedef unsigned short u16;
typedef __attribute__((ext_vector_type(8))) short bf16x8;
typedef __attribute__((ext_vector_type(4))) float f32x4;

#define MFMA16(a, b, c) __builtin_amdgcn_mfma_f32_16x16x32_bf16((a), (b), (c), 0, 0, 0)

__device__ inline u16 f2bf(float f) {
    __hip_bfloat16 h = __float2bfloat16(f);
    return *reinterpret_cast<u16*>(&h);
}

// ---------------------------------------------------------------------------
// QKV projection via MFMA: qkv[o][n] = sum_d w[o][d] * in[d][n] + b[o], bf16 out.
// grid 3072 = 6 o-tiles x 512 n-tiles, block 256 (4 waves; wave w -> o-sub w*16).
// LDS: wT [64 o][k], xT [64 n][k] (both bf16, pad 136), outT [64][72].
// A/B fragments use identical k-map (8*(lane>>4)+e + 32*ks) -> layout-safe.
// ---------------------------------------------------------------------------
__global__ __launch_bounds__(256) void qkv_mfma(const float* __restrict__ in,
                                                const float* __restrict__ wq,
                                                const float* __restrict__ bq,
                                                u16* __restrict__ qkv) {
    __shared__ u16 wT[64][136];
    __shared__ u16 xT[64][136];
    __shared__ float bs[64];
    __shared__ u16 outT[64][72];
    const int bid = blockIdx.x;
    const int o0 = (bid % 6) * 64;
    const int n0 = (bid / 6) * 64;
    const int t = threadIdx.x;

    {   // stage w tile (fp32 -> bf16), [o][k]
        const int o = t >> 2, kq = (t & 3) * 32;
        const float* src = wq + (o0 + o) * 128 + kq;
        #pragma unroll
        for (int itr = 0; itr < 8; ++itr) {
            float4 f = *(const float4*)(src + itr * 4);
            ushort4 hh;
            hh.x = f2bf(f.x); hh.y = f2bf(f.y); hh.z = f2bf(f.z); hh.w = f2bf(f.w);
            *(ushort4*)&wT[o][kq + itr * 4] = hh;
        }
    }
    if (t < 64) bs[t] = bq[o0 + t];
    {   // stage x tile transposed [n][d] (fp32 -> bf16)
        #pragma unroll
        for (int itr = 0; itr < 4; ++itr) {
            const int u = t + itr * 256;
            const int d = u & 127, noct = u >> 7;
            const float* src = in + d * SL + n0 + noct * 8;
            float4 f0 = *(const float4*)src;
            float4 f1 = *(const float4*)(src + 4);
            xT[noct * 8 + 0][d] = f2bf(f0.x);
            xT[noct * 8 + 1][d] = f2bf(f0.y);
            xT[noct * 8 + 2][d] = f2bf(f0.z);
            xT[noct * 8 + 3][d] = f2bf(f0.w);
            xT[noct * 8 + 4][d] = f2bf(f1.x);
            xT[noct * 8 + 5][d] = f2bf(f1.y);
            xT[noct * 8 + 6][d] = f2bf(f1.z);
            xT[noct * 8 + 7][d] = f2bf(f1.w);
        }
    }
    __syncthreads();

    const int lane = t & 63, wv = t >> 6, lo = lane & 15, hi = lane >> 4;
    bf16x8 af[4];
    #pragma unroll
    for (int ks = 0; ks < 4; ++ks)
        af[ks] = *(const bf16x8*)&wT[wv * 16 + lo][hi * 8 + ks * 32];

    #pragma unroll
    for (int nt = 0; nt < 4; ++nt) {
        f32x4 acc = {0.f, 0.f, 0.f, 0.f};
        #pragma unroll
        for (int ks = 0; ks < 4; ++ks) {
            bf16x8 bfr = *(const bf16x8*)&xT[nt * 16 + lo][hi * 8 + ks * 32];
            acc = MFMA16(af[ks], bfr, acc);
        }
        #pragma unroll
        for (int r = 0; r < 4; ++r) {
            const int orow = wv * 16 + hi * 4 + r;   // C-map: row=(lane>>4)*4+r
            outT[orow][nt * 16 + lo] = f2bf(acc[r] + bs[orow]);
        }
    }
    __syncthreads();
    {   // coalesced store
        const int o = t >> 2, seg = t & 3;
        uint4 a = *(uint4*)&outT[o][seg * 16];
        uint4 c2 = *(uint4*)&outT[o][seg * 16 + 8];
        u16* dst = qkv + (o0 + o) * SL + n0 + seg * 16;
        *(uint4*)dst = a;
        *(uint4*)(dst + 8) = c2;
    }
}

// ---------------------------------------------------------------------------
// Fused attention via MFMA. KLEN = keys per attention (256 row / 128 col).
// Block: (h, outer, i-tile of 64). 4 waves, wave w owns queries w*16..+15.
// Scores: A=Q[i][c], B=K[c][j], K=32 -> 1 MFMA per (it,jt). No-max softmax.
// PV every 2 jt: P transits LDS [i][j] (logical) -> A-frag; V native [c][j] -> B-frag.
// Output via LDS transpose (overlay on KT) -> coalesced fp32 stores.
// ---------------------------------------------------------------------------
template<int KLEN>
__global__ __launch_bounds__(256) void attn_kernel(const u16* __restrict__ qkv,
                                                   float* __restrict__ ao) {
    constexpr int NJT = KLEN / 16;
    constexpr int JOCT = KLEN / 8;
    constexpr int IT = (KLEN == 256) ? 4 : 2;
    constexpr int NOUT = SL / KLEN;
    __shared__ u16 QT[64][40];
    __shared__ u16 KT[KLEN][40];
    __shared__ u16 VT[32][KLEN + 8];
    __shared__ u16 PT[64][40];

    const int bid = blockIdx.x;
    const int it = bid & (IT - 1);
    const int outer = (bid / IT) & (NOUT - 1);
    const int h = bid / (IT * NOUT);
    const int base = outer * KLEN;
    const int i0 = it * 64;
    const int t = threadIdx.x;

    {   // stage Q transposed [i][c]
        const int c = t & 31, ioct = t >> 5;
        const u16* src = qkv + (h * 32 + c) * SL + base + i0 + ioct * 8;
        union { uint4 v; u16 s[8]; } u;
        u.v = *(const uint4*)src;
        #pragma unroll
        for (int j = 0; j < 8; ++j) QT[ioct * 8 + j][c] = u.s[j];
    }
    #pragma unroll
    for (int itr = 0; itr < KLEN / 64; ++itr) {   // stage K transposed [j][c]
        const int u0 = t + itr * 256;
        const int c = u0 & 31, joct = u0 >> 5;
        const u16* src = qkv + (128 + h * 32 + c) * SL + base + joct * 8;
        union { uint4 v; u16 s[8]; } u;
        u.v = *(const uint4*)src;
        #pragma unroll
        for (int j = 0; j < 8; ++j) KT[joct * 8 + j][c] = u.s[j];
    }
    #pragma unroll
    for (int itr = 0; itr < KLEN / 64; ++itr) {   // stage V native [c][j]
        const int u0 = t + itr * 256;
        const int joct = u0 & (JOCT - 1), c = u0 / JOCT;
        const u16* src = qkv + (256 + h * 32 + c) * SL + base + joct * 8;
        *(uint4*)&VT[c][joct * 8] = *(const uint4*)src;
    }
    __syncthreads();

    const int lane = t & 63, wv = t >> 6, lo = lane & 15, hi = lane >> 4;

    bf16x8 qfrag = *(const bf16x8*)&QT[wv * 16 + lo][hi * 8];
    f32x4 oacc0 = {0.f, 0.f, 0.f, 0.f}, oacc1 = {0.f, 0.f, 0.f, 0.f};
    float lsum[4] = {0.f, 0.f, 0.f, 0.f};

    #pragma unroll
    for (int jt = 0; jt < NJT; ++jt) {
        bf16x8 kfrag = *(const bf16x8*)&KT[jt * 16 + lo][hi * 8];
        f32x4 z = {0.f, 0.f, 0.f, 0.f};
        f32x4 s = MFMA16(qfrag, kfrag, z);
        #pragma unroll
        for (int r = 0; r < 4; ++r) {
            float p = __expf(s[r]);
            lsum[r] += p;
            PT[wv * 16 + hi * 4 + r][(jt & 1) * 16 + lo] = f2bf(p);
        }
        if (jt & 1) {   // PV over the 32-j window
            bf16x8 pfrag = *(const bf16x8*)&PT[wv * 16 + lo][hi * 8];
            const int jb = (jt - 1) * 16;
            bf16x8 v0 = *(const bf16x8*)&VT[lo][jb + hi * 8];
            bf16x8 v1 = *(const bf16x8*)&VT[16 + lo][jb + hi * 8];
            oacc0 = MFMA16(pfrag, v0, oacc0);
            oacc1 = MFMA16(pfrag, v1, oacc1);
        }
    }
    // reduce lsum across the 16-lane n-group (rows identical within group)
    #pragma unroll
    for (int r = 0; r < 4; ++r) {
        float v = lsum[r];
        v += __shfl_xor(v, 1);
        v += __shfl_xor(v, 2);
        v += __shfl_xor(v, 4);
        v += __shfl_xor(v, 8);
        lsum[r] = 1.f / v;
    }
    __syncthreads();   // all waves done with KT -> overlay OT
    float (*OT)[68] = (float (*)[68])&KT[0][0];   // [32 d][64 i]
    #pragma unroll
    for (int r = 0; r < 4; ++r) {
        OT[lo][wv * 16 + hi * 4 + r]      = oacc0[r] * lsum[r];
        OT[16 + lo][wv * 16 + hi * 4 + r] = oacc1[r] * lsum[r];
    }
    __syncthreads();
    {   // coalesced fp32 store
        const int d = t >> 3, seg = t & 7;
        float* dst = ao + (h * 32 + d) * SL + base + i0 + seg * 8;
        float4 a = *(float4*)&OT[d][seg * 8];
        float4 b2 = *(float4*)&OT[d][seg * 8 + 4];
        *(float4*)dst = a;
        *(float4*)(dst + 4) = b2;
    }
}

// ---------------------------------------------------------------------------
// LN1: out1_T[d][l*128+s] = LN(x + ao)[d][s*256+l]  (native read, T write)
// grid 256 (16 s-tiles x 32 l-tiles), block 128: s = t>>3 (16), l = t&7 (8).
// ---------------------------------------------------------------------------
__global__ __launch_bounds__(128) void ln1_kernel(const float* __restrict__ x,
                                                  const float* __restrict__ ao,
                                                  const float* __restrict__ g,
                                                  const float* __restrict__ be,
                                                  float* __restrict__ outT) {
    __shared__ float sm[8][16][9];
    const int bid = blockIdx.x;
    const int s0 = (bid >> 5) * 16, l0 = (bid & 31) * 8;
    const int t = threadIdx.x;
    const int s = t >> 3, l = t & 7;
    const int p = (s0 + s) * 256 + l0 + l;

    float sum = 0.f, sq = 0.f;
    #pragma unroll 8
    for (int d = 0; d < 128; ++d) {
        float v = x[d * SL + p] + ao[d * SL + p];
        sum += v; sq += v * v;
    }
    const float mean = sum * (1.f / 128.f);
    const float var = sq * (1.f / 128.f) - mean * mean;
    const float rstd = rsqrtf(var + EPS_LN);

    for (int dc = 0; dc < 16; ++dc) {
        #pragma unroll
        for (int dd = 0; dd < 8; ++dd) {
            const int d = dc * 8 + dd;
            float v = x[d * SL + p] + ao[d * SL + p];
            sm[dd][s][l] = (v - mean) * rstd * g[d] + be[d];
        }
        __syncthreads();
        {
            const int r = t & 63, half = t >> 6;
            const int dd = r >> 3, ll = r & 7, d = dc * 8 + dd;
            float tmp[8];
            #pragma unroll
            for (int ss = 0; ss < 8; ++ss) tmp[ss] = sm[dd][half * 8 + ss][ll];
            float* dst = outT + d * SL + (l0 + ll) * 128 + s0 + half * 8;
            *(float4*)dst = make_float4(tmp[0], tmp[1], tmp[2], tmp[3]);
            *(float4*)(dst + 4) = make_float4(tmp[4], tmp[5], tmp[6], tmp[7]);
        }
        __syncthreads();
    }
}

// ---------------------------------------------------------------------------
// LN2: out[d][s*256+l] = LN(out1_T + ao_T)[d][l*128+s]  (T read, native write)
// grid 256 (16 l-tiles x 16 s-tiles), block 128: l = t>>3 (16), s = t&7 (8).
// ---------------------------------------------------------------------------
__global__ __launch_bounds__(128) void ln2_kernel(const float* __restrict__ aT,
                                                  const float* __restrict__ rT,
                                                  const float* __restrict__ g,
                                                  const float* __restrict__ be,
                                                  float* __restrict__ outp) {
    __shared__ float sm[8][16][9];
    const int bid = blockIdx.x;
    const int l0 = (bid & 15) * 16, s0 = (bid >> 4) * 8;
    const int t = threadIdx.x;
    const int l = t >> 3, s = t & 7;
    const int p = (l0 + l) * 128 + s0 + s;

    float sum = 0.f, sq = 0.f;
    #pragma unroll 8
    for (int d = 0; d < 128; ++d) {
        float v = aT[d * SL + p] + rT[d * SL + p];
        sum += v; sq += v * v;
    }
    const float mean = sum * (1.f / 128.f);
    const float var = sq * (1.f / 128.f) - mean * mean;
    const float rstd = rsqrtf(var + EPS_LN);

    for (int dc = 0; dc < 16; ++dc) {
        #pragma unroll
        for (int dd = 0; dd < 8; ++dd) {
            const int d = dc * 8 + dd;
            float v = aT[d * SL + p] + rT[d * SL + p];
            sm[dd][l][s] = (v - mean) * rstd * g[d] + be[d];
        }
        __syncthreads();
        {
            const int r = t & 63, half = t >> 6;
            const int dd = r >> 3, ss = r & 7, d = dc * 8 + dd;
            float tmp[8];
            #pragma unroll
            for (int ll = 0; ll < 8; ++ll) tmp[ll] = sm[dd][half * 8 + ll][ss];
            float* dst = outp + d * SL + (s0 + ss) * 256 + l0 + half * 8;
            *(float4*)dst = make_float4(tmp[0], tmp[1], tmp[2], tmp[3]);
            *(float4*)(dst + 4) = make_float4(tmp[4], tmp[5], tmp[6], tmp[7]);
        }
        __syncthreads();
    }
}

// ---------------------------------------------------------------------------
extern "C" void kernel_launch(void* const* d_in, const int* in_sizes, int n_in,
                              void* d_out, int out_size, void* d_ws, size_t ws_size,
                              hipStream_t stream) {
    const float* x     = (const float*)d_in[0];
    const float* w_row = (const float*)d_in[1];
    const float* b_row = (const float*)d_in[2];
    const float* w_col = (const float*)d_in[3];
    const float* b_col = (const float*)d_in[4];
    const float* g1    = (const float*)d_in[5];
    const float* be1   = (const float*)d_in[6];
    const float* g2    = (const float*)d_in[7];
    const float* be2   = (const float*)d_in[8];
    float* out = (float*)d_out;

    // ws: qkv bf16 (24MB) | ao fp32 (16MB) | out1_T fp32 (16MB)
    char* base = (char*)d_ws;
    u16*   qkvb = (u16*)base;
    float* ao   = (float*)(base + (size_t)384 * SL * 2);
    float* o1T  = (float*)(base + (size_t)384 * SL * 2 + (size_t)128 * SL * 4);

    qkv_mfma<<<3072, 256, 0, stream>>>(x, w_row, b_row, qkvb);
    attn_kernel<256><<<2048, 256, 0, stream>>>(qkvb, ao);
    ln1_kernel<<<256, 128, 0, stream>>>(x, ao, g1, be1, o1T);
    qkv_mfma<<<3072, 256, 0, stream>>>(o1T, w_col, b_col, qkvb);
    attn_kernel<128><<<2048, 256, 0, stream>>>(qkvb, ao);
    ln2_kernel<<<256, 128, 0, stream>>>(o1T, ao, g2, be2, out);
}

// Round 5
// 139.276 us; speedup vs baseline: 3.6704x; 1.1749x over previous
//
#include <hip/hip_runtime.h>
#include <hip/hip_bf16.h>

#define SL     32768
#define EPS_LN 1e-5f

typedef unsigned short u16;
typedef __attribute__((ext_vector_type(8))) short bf16x8;
typedef __attribute__((ext_vector_type(4))) float f32x4;

#define MFMA16(a, b, c) __builtin_amdgcn_mfma_f32_16x16x32_bf16((a), (b), (c), 0, 0, 0)

__device__ inline u16 f2bf(float f) {
    __hip_bfloat16 h = __float2bfloat16(f);
    return *reinterpret_cast<u16*>(&h);
}
__device__ inline float bf2f(u16 u) {
    unsigned v = ((unsigned)u) << 16;
    float f;
    __builtin_memcpy(&f, &v, 4);
    return f;
}

// ---------------------------------------------------------------------------
// QKV projection via MFMA (unchanged from round 4).
// ---------------------------------------------------------------------------
__global__ __launch_bounds__(256) void qkv_mfma(const float* __restrict__ in,
                                                const float* __restrict__ wq,
                                                const float* __restrict__ bq,
                                                u16* __restrict__ qkv) {
    __shared__ u16 wT[64][136];
    __shared__ u16 xT[64][136];
    __shared__ float bs[64];
    __shared__ u16 outT[64][72];
    const int bid = blockIdx.x;
    const int o0 = (bid % 6) * 64;
    const int n0 = (bid / 6) * 64;
    const int t = threadIdx.x;

    {
        const int o = t >> 2, kq = (t & 3) * 32;
        const float* src = wq + (o0 + o) * 128 + kq;
        #pragma unroll
        for (int itr = 0; itr < 8; ++itr) {
            float4 f = *(const float4*)(src + itr * 4);
            ushort4 hh;
            hh.x = f2bf(f.x); hh.y = f2bf(f.y); hh.z = f2bf(f.z); hh.w = f2bf(f.w);
            *(ushort4*)&wT[o][kq + itr * 4] = hh;
        }
    }
    if (t < 64) bs[t] = bq[o0 + t];
    {
        #pragma unroll
        for (int itr = 0; itr < 4; ++itr) {
            const int u = t + itr * 256;
            const int d = u & 127, noct = u >> 7;
            const float* src = in + d * SL + n0 + noct * 8;
            float4 f0 = *(const float4*)src;
            float4 f1 = *(const float4*)(src + 4);
            xT[noct * 8 + 0][d] = f2bf(f0.x);
            xT[noct * 8 + 1][d] = f2bf(f0.y);
            xT[noct * 8 + 2][d] = f2bf(f0.z);
            xT[noct * 8 + 3][d] = f2bf(f0.w);
            xT[noct * 8 + 4][d] = f2bf(f1.x);
            xT[noct * 8 + 5][d] = f2bf(f1.y);
            xT[noct * 8 + 6][d] = f2bf(f1.z);
            xT[noct * 8 + 7][d] = f2bf(f1.w);
        }
    }
    __syncthreads();

    const int lane = t & 63, wv = t >> 6, lo = lane & 15, hi = lane >> 4;
    bf16x8 af[4];
    #pragma unroll
    for (int ks = 0; ks < 4; ++ks)
        af[ks] = *(const bf16x8*)&wT[wv * 16 + lo][hi * 8 + ks * 32];

    #pragma unroll
    for (int nt = 0; nt < 4; ++nt) {
        f32x4 acc = {0.f, 0.f, 0.f, 0.f};
        #pragma unroll
        for (int ks = 0; ks < 4; ++ks) {
            bf16x8 bfr = *(const bf16x8*)&xT[nt * 16 + lo][hi * 8 + ks * 32];
            acc = MFMA16(af[ks], bfr, acc);
        }
        #pragma unroll
        for (int r = 0; r < 4; ++r) {
            const int orow = wv * 16 + hi * 4 + r;
            outT[orow][nt * 16 + lo] = f2bf(acc[r] + bs[orow]);
        }
    }
    __syncthreads();
    {
        const int o = t >> 2, seg = t & 3;
        uint4 a = *(uint4*)&outT[o][seg * 16];
        uint4 c2 = *(uint4*)&outT[o][seg * 16 + 8];
        u16* dst = qkv + (o0 + o) * SL + n0 + seg * 16;
        *(uint4*)dst = a;
        *(uint4*)(dst + 8) = c2;
    }
}

// ---------------------------------------------------------------------------
// Fused attention via MFMA (round-4 structure, output now bf16).
// ---------------------------------------------------------------------------
template<int KLEN>
__global__ __launch_bounds__(256) void attn_kernel(const u16* __restrict__ qkv,
                                                   u16* __restrict__ ao) {
    constexpr int NJT = KLEN / 16;
    constexpr int JOCT = KLEN / 8;
    constexpr int IT = (KLEN == 256) ? 4 : 2;
    constexpr int NOUT = SL / KLEN;
    __shared__ u16 QT[64][40];
    __shared__ u16 KT[KLEN][40];
    __shared__ u16 VT[32][KLEN + 8];
    __shared__ u16 PT[64][40];

    const int bid = blockIdx.x;
    const int it = bid & (IT - 1);
    const int outer = (bid / IT) & (NOUT - 1);
    const int h = bid / (IT * NOUT);
    const int base = outer * KLEN;
    const int i0 = it * 64;
    const int t = threadIdx.x;

    {
        const int c = t & 31, ioct = t >> 5;
        const u16* src = qkv + (h * 32 + c) * SL + base + i0 + ioct * 8;
        union { uint4 v; u16 s[8]; } u;
        u.v = *(const uint4*)src;
        #pragma unroll
        for (int j = 0; j < 8; ++j) QT[ioct * 8 + j][c] = u.s[j];
    }
    #pragma unroll
    for (int itr = 0; itr < KLEN / 64; ++itr) {
        const int u0 = t + itr * 256;
        const int c = u0 & 31, joct = u0 >> 5;
        const u16* src = qkv + (128 + h * 32 + c) * SL + base + joct * 8;
        union { uint4 v; u16 s[8]; } u;
        u.v = *(const uint4*)src;
        #pragma unroll
        for (int j = 0; j < 8; ++j) KT[joct * 8 + j][c] = u.s[j];
    }
    #pragma unroll
    for (int itr = 0; itr < KLEN / 64; ++itr) {
        const int u0 = t + itr * 256;
        const int joct = u0 & (JOCT - 1), c = u0 / JOCT;
        const u16* src = qkv + (256 + h * 32 + c) * SL + base + joct * 8;
        *(uint4*)&VT[c][joct * 8] = *(const uint4*)src;
    }
    __syncthreads();

    const int lane = t & 63, wv = t >> 6, lo = lane & 15, hi = lane >> 4;

    bf16x8 qfrag = *(const bf16x8*)&QT[wv * 16 + lo][hi * 8];
    f32x4 oacc0 = {0.f, 0.f, 0.f, 0.f}, oacc1 = {0.f, 0.f, 0.f, 0.f};
    float lsum[4] = {0.f, 0.f, 0.f, 0.f};

    #pragma unroll
    for (int jt = 0; jt < NJT; ++jt) {
        bf16x8 kfrag = *(const bf16x8*)&KT[jt * 16 + lo][hi * 8];
        f32x4 z = {0.f, 0.f, 0.f, 0.f};
        f32x4 s = MFMA16(qfrag, kfrag, z);
        #pragma unroll
        for (int r = 0; r < 4; ++r) {
            float p = __expf(s[r]);
            lsum[r] += p;
            PT[wv * 16 + hi * 4 + r][(jt & 1) * 16 + lo] = f2bf(p);
        }
        if (jt & 1) {
            bf16x8 pfrag = *(const bf16x8*)&PT[wv * 16 + lo][hi * 8];
            const int jb = (jt - 1) * 16;
            bf16x8 v0 = *(const bf16x8*)&VT[lo][jb + hi * 8];
            bf16x8 v1 = *(const bf16x8*)&VT[16 + lo][jb + hi * 8];
            oacc0 = MFMA16(pfrag, v0, oacc0);
            oacc1 = MFMA16(pfrag, v1, oacc1);
        }
    }
    #pragma unroll
    for (int r = 0; r < 4; ++r) {
        float v = lsum[r];
        v += __shfl_xor(v, 1);
        v += __shfl_xor(v, 2);
        v += __shfl_xor(v, 4);
        v += __shfl_xor(v, 8);
        lsum[r] = 1.f / v;
    }
    __syncthreads();
    u16 (*OTu)[72] = (u16 (*)[72])&KT[0][0];   // [32 d][64 i] bf16
    #pragma unroll
    for (int r = 0; r < 4; ++r) {
        OTu[lo][wv * 16 + hi * 4 + r]      = f2bf(oacc0[r] * lsum[r]);
        OTu[16 + lo][wv * 16 + hi * 4 + r] = f2bf(oacc1[r] * lsum[r]);
    }
    __syncthreads();
    {
        const int d = t >> 3, seg = t & 7;
        u16* dst = ao + (h * 32 + d) * SL + base + i0 + seg * 8;
        *(uint4*)dst = *(uint4*)&OTu[d][seg * 8];
    }
}

// ---------------------------------------------------------------------------
// stats: per-position mean/rstd of in0(fp32) + in1(bf16). 4 threads/position
// (32 d each), float4 over positions, shfl_xor(16/32) merge. grid 256 x 128.
// ---------------------------------------------------------------------------
__global__ __launch_bounds__(128) void stats_kernel(const float* __restrict__ in0,
                                                    const u16* __restrict__ in1,
                                                    float2* __restrict__ stats) {
    const int t = threadIdx.x;
    const int w = t >> 6, lane = t & 63;
    const int q = lane >> 4, pl = lane & 15;
    const int p = blockIdx.x * 128 + w * 64 + pl * 4;
    const float* b0 = in0 + (size_t)q * 32 * SL + p;
    const u16*  b1 = in1 + (size_t)q * 32 * SL + p;

    float s[4] = {0.f, 0.f, 0.f, 0.f};
    float ss[4] = {0.f, 0.f, 0.f, 0.f};
    #pragma unroll 4
    for (int dd = 0; dd < 32; ++dd) {
        float4 f = *(const float4*)(b0 + (size_t)dd * SL);
        ushort4 h = *(const ushort4*)(b1 + (size_t)dd * SL);
        float v0 = f.x + bf2f(h.x);
        float v1 = f.y + bf2f(h.y);
        float v2 = f.z + bf2f(h.z);
        float v3 = f.w + bf2f(h.w);
        s[0] += v0; ss[0] += v0 * v0;
        s[1] += v1; ss[1] += v1 * v1;
        s[2] += v2; ss[2] += v2 * v2;
        s[3] += v3; ss[3] += v3 * v3;
    }
    #pragma unroll
    for (int k = 0; k < 4; ++k) {
        s[k]  += __shfl_xor(s[k], 16);
        s[k]  += __shfl_xor(s[k], 32);
        ss[k] += __shfl_xor(ss[k], 16);
        ss[k] += __shfl_xor(ss[k], 32);
    }
    if (q == 0) {
        #pragma unroll
        for (int k = 0; k < 4; ++k) {
            const float mean = s[k] * (1.f / 128.f);
            const float var  = ss[k] * (1.f / 128.f) - mean * mean;
            stats[p + k] = make_float2(mean, rsqrtf(var + EPS_LN));
        }
    }
}

// ---------------------------------------------------------------------------
// apply: out[d][c*NOUT+r] = ((in0+in1)[d][r*NIN+c] - mean)*rstd*g[d] + be[d]
// (normalize + transpose). grid = 8 d-chunks x (NOUT/16) x (NIN/16), block 256.
// Phase A: 16 contiguous in-elems/thread -> LDS [16d][16c][17r].
// Phase B: 16 contiguous out-elems/thread.
// ---------------------------------------------------------------------------
template<int NIN>
__global__ __launch_bounds__(256) void apply_kernel(const float* __restrict__ in0,
                                                    const u16* __restrict__ in1,
                                                    const float2* __restrict__ stats,
                                                    const float* __restrict__ g,
                                                    const float* __restrict__ be,
                                                    float* __restrict__ outp) {
    constexpr int NOUT = SL / NIN;
    constexpr int RT = NOUT / 16;
    constexpr int CT = NIN / 16;
    __shared__ float sm[16][16][17];
    __shared__ float2 st[16][16];
    const int bid = blockIdx.x;
    const int dc  = bid / (RT * CT);
    const int rem = bid % (RT * CT);
    const int r0 = (rem / CT) * 16;
    const int c0 = (rem % CT) * 16;
    const int t = threadIdx.x;

    {
        const int r = t >> 4, c = t & 15;
        st[r][c] = stats[(r0 + r) * NIN + c0 + c];
    }
    __syncthreads();

    const int d16 = t >> 4;
    const int d = dc * 16 + d16;
    const float gd = g[d], bd = be[d];
    {
        const int r = t & 15;
        const float* p0 = in0 + (size_t)d * SL + (r0 + r) * NIN + c0;
        const u16*  p1 = in1 + (size_t)d * SL + (r0 + r) * NIN + c0;
        float fv[16];
        #pragma unroll
        for (int k = 0; k < 4; ++k) *(float4*)&fv[k * 4] = *(const float4*)(p0 + k * 4);
        union { uint4 v[2]; u16 u[16]; } U;
        U.v[0] = *(const uint4*)p1;
        U.v[1] = *(const uint4*)(p1 + 8);
        #pragma unroll
        for (int c = 0; c < 16; ++c) {
            const float v = fv[c] + bf2f(U.u[c]);
            const float2 mz = st[r][c];
            sm[d16][c][r] = (v - mz.x) * mz.y * gd + bd;
        }
    }
    __syncthreads();
    {
        const int c = t & 15;
        float ov[16];
        #pragma unroll
        for (int k = 0; k < 4; ++k) *(float4*)&ov[k * 4] = *(const float4*)&sm[d16][c][k * 4];
        float* dst = outp + (size_t)d * SL + (c0 + c) * NOUT + r0;
        #pragma unroll
        for (int k = 0; k < 4; ++k) *(float4*)(dst + k * 4) = *(const float4*)&ov[k * 4];
    }
}

// ---------------------------------------------------------------------------
extern "C" void kernel_launch(void* const* d_in, const int* in_sizes, int n_in,
                              void* d_out, int out_size, void* d_ws, size_t ws_size,
                              hipStream_t stream) {
    const float* x     = (const float*)d_in[0];
    const float* w_row = (const float*)d_in[1];
    const float* b_row = (const float*)d_in[2];
    const float* w_col = (const float*)d_in[3];
    const float* b_col = (const float*)d_in[4];
    const float* g1    = (const float*)d_in[5];
    const float* be1   = (const float*)d_in[6];
    const float* g2    = (const float*)d_in[7];
    const float* be2   = (const float*)d_in[8];
    float* out = (float*)d_out;

    // ws: qkv bf16 24MB | ao bf16 8MB | o1T fp32 16MB | stats 256KB
    char* base = (char*)d_ws;
    u16*    qkvb  = (u16*)base;
    u16*    ao16  = (u16*)(base + (size_t)384 * SL * 2);
    float*  o1T   = (float*)(base + (size_t)384 * SL * 2 + (size_t)128 * SL * 2);
    float2* stats = (float2*)(base + (size_t)384 * SL * 2 + (size_t)128 * SL * 2
                                   + (size_t)128 * SL * 4);

    qkv_mfma<<<3072, 256, 0, stream>>>(x, w_row, b_row, qkvb);
    attn_kernel<256><<<2048, 256, 0, stream>>>(qkvb, ao16);
    stats_kernel<<<256, 128, 0, stream>>>(x, ao16, stats);
    apply_kernel<256><<<1024, 256, 0, stream>>>(x, ao16, stats, g1, be1, o1T);
    qkv_mfma<<<3072, 256, 0, stream>>>(o1T, w_col, b_col, qkvb);
    attn_kernel<128><<<2048, 256, 0, stream>>>(qkvb, ao16);
    stats_kernel<<<256, 128, 0, stream>>>(o1T, ao16, stats);
    apply_kernel<128><<<1024, 256, 0, stream>>>(o1T, ao16, stats, g2, be2, out);
}

// Round 6
// 125.392 us; speedup vs baseline: 4.0768x; 1.1107x over previous
//
#include <hip/hip_runtime.h>
#include <hip/hip_bf16.h>

#define SL     32768
#define EPS_LN 1e-5f

typedef unsigned short u16;
typedef __attribute__((ext_vector_type(8))) short bf16x8;
typedef __attribute__((ext_vector_type(4))) float f32x4;

#define MFMA16(a, b, c) __builtin_amdgcn_mfma_f32_16x16x32_bf16((a), (b), (c), 0, 0, 0)

__device__ inline u16 f2bf(float f) {
    __hip_bfloat16 h = __float2bfloat16(f);
    return *reinterpret_cast<u16*>(&h);
}
__device__ inline float bf2f(u16 u) {
    unsigned v = ((unsigned)u) << 16;
    float f;
    __builtin_memcpy(&f, &v, 4);
    return f;
}
__device__ inline uint4 pack8(float4 a, float4 b) {
    union { uint4 v; u16 u[8]; } U;
    U.u[0] = f2bf(a.x); U.u[1] = f2bf(a.y); U.u[2] = f2bf(a.z); U.u[3] = f2bf(a.w);
    U.u[4] = f2bf(b.x); U.u[5] = f2bf(b.y); U.u[6] = f2bf(b.z); U.u[7] = f2bf(b.w);
    return U.v;
}

// ---------------------------------------------------------------------------
// cast: x, w_row, w_col -> bf16 copies. 8 elems/thread.
// ---------------------------------------------------------------------------
__global__ __launch_bounds__(256) void cast_kernel(const float* __restrict__ x,
                                                   const float* __restrict__ wr,
                                                   const float* __restrict__ wc,
                                                   u16* __restrict__ xb,
                                                   u16* __restrict__ wrb,
                                                   u16* __restrict__ wcb) {
    const int i = blockIdx.x * 256 + threadIdx.x;
    const int NX = 128 * SL / 8;       // 524288
    const int NW = 384 * 128 / 8;      // 6144
    const float* src; u16* dst; int j;
    if (i < NX)               { src = x;  dst = xb;  j = i; }
    else if (i < NX + NW)     { src = wr; dst = wrb; j = i - NX; }
    else if (i < NX + 2 * NW) { src = wc; dst = wcb; j = i - NX - NW; }
    else return;
    float4 a = ((const float4*)src)[j * 2];
    float4 b = ((const float4*)src)[j * 2 + 1];
    ((uint4*)dst)[j] = pack8(a, b);
}

// ---------------------------------------------------------------------------
// QKV via MFMA, bf16 in/out. grid 1536 = 3 o-tiles(128) x 512 n-tiles(64).
// 4 waves; wave w owns o rows w*32..+31 (2 x 16-row frags) x all 64 n.
// ---------------------------------------------------------------------------
__global__ __launch_bounds__(256) void qkv_mfma(const u16* __restrict__ in,
                                                const u16* __restrict__ wb,
                                                const float* __restrict__ bq,
                                                u16* __restrict__ qkv) {
    __shared__ u16 wT[128][136];
    __shared__ u16 xT[64][136];
    __shared__ float bs[128];
    __shared__ u16 outT[128][72];
    const int bid = blockIdx.x;
    const int o0 = (bid % 3) * 128;
    const int n0 = (bid / 3) * 64;
    const int t = threadIdx.x;

    {   // stage w [o][k] via uint4 copies
        const int o = t >> 1, kh = (t & 1) * 64;
        const uint4* s4 = (const uint4*)(wb + (size_t)(o0 + o) * 128 + kh);
        uint4* dst = (uint4*)&wT[o][kh];
        #pragma unroll
        for (int k = 0; k < 8; ++k) dst[k] = s4[k];
    }
    if (t < 128) bs[t] = bq[o0 + t];
    {   // stage x transposed [n][d]
        #pragma unroll
        for (int itr = 0; itr < 4; ++itr) {
            const int u = t + itr * 256;
            const int d = u & 127, noct = u >> 7;
            union { uint4 v; u16 s[8]; } U;
            U.v = *(const uint4*)(in + (size_t)d * SL + n0 + noct * 8);
            #pragma unroll
            for (int j = 0; j < 8; ++j) xT[noct * 8 + j][d] = U.s[j];
        }
    }
    __syncthreads();

    const int lane = t & 63, wv = t >> 6, lo = lane & 15, hi = lane >> 4;
    bf16x8 af[2][4];
    #pragma unroll
    for (int om = 0; om < 2; ++om)
        #pragma unroll
        for (int ks = 0; ks < 4; ++ks)
            af[om][ks] = *(const bf16x8*)&wT[wv * 32 + om * 16 + lo][hi * 8 + ks * 32];

    #pragma unroll
    for (int nt = 0; nt < 4; ++nt) {
        bf16x8 bfr[4];
        #pragma unroll
        for (int ks = 0; ks < 4; ++ks)
            bfr[ks] = *(const bf16x8*)&xT[nt * 16 + lo][hi * 8 + ks * 32];
        #pragma unroll
        for (int om = 0; om < 2; ++om) {
            f32x4 acc = {0.f, 0.f, 0.f, 0.f};
            #pragma unroll
            for (int ks = 0; ks < 4; ++ks)
                acc = MFMA16(af[om][ks], bfr[ks], acc);
            #pragma unroll
            for (int r = 0; r < 4; ++r) {
                const int orow = wv * 32 + om * 16 + hi * 4 + r;
                outT[orow][nt * 16 + lo] = f2bf(acc[r] + bs[orow]);
            }
        }
    }
    __syncthreads();
    {   // coalesced store: 64 B per thread
        const int o = t >> 1, nh = (t & 1) * 32;
        u16* dst = qkv + (size_t)(o0 + o) * SL + n0 + nh;
        const uint4* s4 = (const uint4*)&outT[o][nh];
        #pragma unroll
        for (int k = 0; k < 4; ++k) ((uint4*)dst)[k] = s4[k];
    }
}

// ---------------------------------------------------------------------------
// Fused attention via MFMA (unchanged structure; bf16 in/out).
// ---------------------------------------------------------------------------
template<int KLEN>
__global__ __launch_bounds__(256) void attn_kernel(const u16* __restrict__ qkv,
                                                   u16* __restrict__ ao) {
    constexpr int NJT = KLEN / 16;
    constexpr int JOCT = KLEN / 8;
    constexpr int IT = (KLEN == 256) ? 4 : 2;
    constexpr int NOUT = SL / KLEN;
    __shared__ u16 QT[64][40];
    __shared__ u16 KT[KLEN][40];
    __shared__ u16 VT[32][KLEN + 8];
    __shared__ u16 PT[64][40];

    const int bid = blockIdx.x;
    const int it = bid & (IT - 1);
    const int outer = (bid / IT) & (NOUT - 1);
    const int h = bid / (IT * NOUT);
    const int base = outer * KLEN;
    const int i0 = it * 64;
    const int t = threadIdx.x;

    {
        const int c = t & 31, ioct = t >> 5;
        const u16* src = qkv + (size_t)(h * 32 + c) * SL + base + i0 + ioct * 8;
        union { uint4 v; u16 s[8]; } u;
        u.v = *(const uint4*)src;
        #pragma unroll
        for (int j = 0; j < 8; ++j) QT[ioct * 8 + j][c] = u.s[j];
    }
    #pragma unroll
    for (int itr = 0; itr < KLEN / 64; ++itr) {
        const int u0 = t + itr * 256;
        const int c = u0 & 31, joct = u0 >> 5;
        const u16* src = qkv + (size_t)(128 + h * 32 + c) * SL + base + joct * 8;
        union { uint4 v; u16 s[8]; } u;
        u.v = *(const uint4*)src;
        #pragma unroll
        for (int j = 0; j < 8; ++j) KT[joct * 8 + j][c] = u.s[j];
    }
    #pragma unroll
    for (int itr = 0; itr < KLEN / 64; ++itr) {
        const int u0 = t + itr * 256;
        const int joct = u0 & (JOCT - 1), c = u0 / JOCT;
        const u16* src = qkv + (size_t)(256 + h * 32 + c) * SL + base + joct * 8;
        *(uint4*)&VT[c][joct * 8] = *(const uint4*)src;
    }
    __syncthreads();

    const int lane = t & 63, wv = t >> 6, lo = lane & 15, hi = lane >> 4;

    bf16x8 qfrag = *(const bf16x8*)&QT[wv * 16 + lo][hi * 8];
    f32x4 oacc0 = {0.f, 0.f, 0.f, 0.f}, oacc1 = {0.f, 0.f, 0.f, 0.f};
    float lsum[4] = {0.f, 0.f, 0.f, 0.f};

    #pragma unroll
    for (int jt = 0; jt < NJT; ++jt) {
        bf16x8 kfrag = *(const bf16x8*)&KT[jt * 16 + lo][hi * 8];
        f32x4 z = {0.f, 0.f, 0.f, 0.f};
        f32x4 s = MFMA16(qfrag, kfrag, z);
        #pragma unroll
        for (int r = 0; r < 4; ++r) {
            float p = __expf(s[r]);
            lsum[r] += p;
            PT[wv * 16 + hi * 4 + r][(jt & 1) * 16 + lo] = f2bf(p);
        }
        if (jt & 1) {
            bf16x8 pfrag = *(const bf16x8*)&PT[wv * 16 + lo][hi * 8];
            const int jb = (jt - 1) * 16;
            bf16x8 v0 = *(const bf16x8*)&VT[lo][jb + hi * 8];
            bf16x8 v1 = *(const bf16x8*)&VT[16 + lo][jb + hi * 8];
            oacc0 = MFMA16(pfrag, v0, oacc0);
            oacc1 = MFMA16(pfrag, v1, oacc1);
        }
    }
    #pragma unroll
    for (int r = 0; r < 4; ++r) {
        float v = lsum[r];
        v += __shfl_xor(v, 1);
        v += __shfl_xor(v, 2);
        v += __shfl_xor(v, 4);
        v += __shfl_xor(v, 8);
        lsum[r] = 1.f / v;
    }
    __syncthreads();
    u16 (*OTu)[72] = (u16 (*)[72])&KT[0][0];   // [32 d][64 i] bf16
    #pragma unroll
    for (int r = 0; r < 4; ++r) {
        OTu[lo][wv * 16 + hi * 4 + r]      = f2bf(oacc0[r] * lsum[r]);
        OTu[16 + lo][wv * 16 + hi * 4 + r] = f2bf(oacc1[r] * lsum[r]);
    }
    __syncthreads();
    {
        const int d = t >> 3, seg = t & 7;
        u16* dst = ao + (size_t)(h * 32 + d) * SL + base + i0 + seg * 8;
        *(uint4*)dst = *(uint4*)&OTu[d][seg * 8];
    }
}

// ---------------------------------------------------------------------------
// stats: per-position mean/rstd of in0(T0) + in1(bf16). grid 256 x 128.
// ---------------------------------------------------------------------------
template<typename T0>
__global__ __launch_bounds__(128) void stats_kernel(const T0* __restrict__ in0,
                                                    const u16* __restrict__ in1,
                                                    float2* __restrict__ stats) {
    const int t = threadIdx.x;
    const int w = t >> 6, lane = t & 63;
    const int q = lane >> 4, pl = lane & 15;
    const int p = blockIdx.x * 128 + w * 64 + pl * 4;
    const T0* b0 = in0 + (size_t)q * 32 * SL + p;
    const u16* b1 = in1 + (size_t)q * 32 * SL + p;

    float s[4] = {0.f, 0.f, 0.f, 0.f};
    float ss[4] = {0.f, 0.f, 0.f, 0.f};
    #pragma unroll 4
    for (int dd = 0; dd < 32; ++dd) {
        float v[4];
        if constexpr (sizeof(T0) == 4) {
            float4 f = *(const float4*)(b0 + (size_t)dd * SL);
            v[0] = f.x; v[1] = f.y; v[2] = f.z; v[3] = f.w;
        } else {
            ushort4 h = *(const ushort4*)(b0 + (size_t)dd * SL);
            v[0] = bf2f(h.x); v[1] = bf2f(h.y); v[2] = bf2f(h.z); v[3] = bf2f(h.w);
        }
        ushort4 h1 = *(const ushort4*)(b1 + (size_t)dd * SL);
        v[0] += bf2f(h1.x); v[1] += bf2f(h1.y); v[2] += bf2f(h1.z); v[3] += bf2f(h1.w);
        #pragma unroll
        for (int k = 0; k < 4; ++k) { s[k] += v[k]; ss[k] += v[k] * v[k]; }
    }
    #pragma unroll
    for (int k = 0; k < 4; ++k) {
        s[k]  += __shfl_xor(s[k], 16);
        s[k]  += __shfl_xor(s[k], 32);
        ss[k] += __shfl_xor(ss[k], 16);
        ss[k] += __shfl_xor(ss[k], 32);
    }
    if (q == 0) {
        #pragma unroll
        for (int k = 0; k < 4; ++k) {
            const float mean = s[k] * (1.f / 128.f);
            const float var  = ss[k] * (1.f / 128.f) - mean * mean;
            stats[p + k] = make_float2(mean, rsqrtf(var + EPS_LN));
        }
    }
}

// ---------------------------------------------------------------------------
// apply: normalize + transpose. T0 = residual type, TO = output type.
// ---------------------------------------------------------------------------
template<int NIN, typename T0, typename TO>
__global__ __launch_bounds__(256) void apply_kernel(const T0* __restrict__ in0,
                                                    const u16* __restrict__ in1,
                                                    const float2* __restrict__ stats,
                                                    const float* __restrict__ g,
                                                    const float* __restrict__ be,
                                                    TO* __restrict__ outp) {
    constexpr int NOUT = SL / NIN;
    constexpr int RT = NOUT / 16;
    constexpr int CT = NIN / 16;
    __shared__ float sm[16][16][17];
    __shared__ float2 st[16][16];
    const int bid = blockIdx.x;
    const int dc  = bid / (RT * CT);
    const int rem = bid % (RT * CT);
    const int r0 = (rem / CT) * 16;
    const int c0 = (rem % CT) * 16;
    const int t = threadIdx.x;

    {
        const int r = t >> 4, c = t & 15;
        st[r][c] = stats[(r0 + r) * NIN + c0 + c];
    }
    __syncthreads();

    const int d16 = t >> 4;
    const int d = dc * 16 + d16;
    const float gd = g[d], bd = be[d];
    {
        const int r = t & 15;
        float fv[16];
        if constexpr (sizeof(T0) == 4) {
            const float* p0 = in0 + (size_t)d * SL + (r0 + r) * NIN + c0;
            #pragma unroll
            for (int k = 0; k < 4; ++k) *(float4*)&fv[k * 4] = *(const float4*)(p0 + k * 4);
        } else {
            const u16* p0 = (const u16*)in0 + (size_t)d * SL + (r0 + r) * NIN + c0;
            union { uint4 v[2]; u16 u[16]; } A;
            A.v[0] = *(const uint4*)p0;
            A.v[1] = *(const uint4*)(p0 + 8);
            #pragma unroll
            for (int c = 0; c < 16; ++c) fv[c] = bf2f(A.u[c]);
        }
        const u16* p1 = in1 + (size_t)d * SL + (r0 + r) * NIN + c0;
        union { uint4 v[2]; u16 u[16]; } B;
        B.v[0] = *(const uint4*)p1;
        B.v[1] = *(const uint4*)(p1 + 8);
        #pragma unroll
        for (int c = 0; c < 16; ++c) {
            const float v = fv[c] + bf2f(B.u[c]);
            const float2 mz = st[r][c];
            sm[d16][c][r] = (v - mz.x) * mz.y * gd + bd;
        }
    }
    __syncthreads();
    {
        const int c = t & 15;
        float ov[16];
        #pragma unroll
        for (int k = 0; k < 4; ++k) *(float4*)&ov[k * 4] = *(const float4*)&sm[d16][c][k * 4];
        if constexpr (sizeof(TO) == 4) {
            float* dst = (float*)outp + (size_t)d * SL + (c0 + c) * NOUT + r0;
            #pragma unroll
            for (int k = 0; k < 4; ++k) *(float4*)(dst + k * 4) = *(const float4*)&ov[k * 4];
        } else {
            u16* dst = (u16*)outp + (size_t)d * SL + (c0 + c) * NOUT + r0;
            union { uint4 v[2]; u16 u[16]; } O;
            #pragma unroll
            for (int k = 0; k < 16; ++k) O.u[k] = f2bf(ov[k]);
            *(uint4*)dst = O.v[0];
            *(uint4*)(dst + 8) = O.v[1];
        }
    }
}

// ---------------------------------------------------------------------------
extern "C" void kernel_launch(void* const* d_in, const int* in_sizes, int n_in,
                              void* d_out, int out_size, void* d_ws, size_t ws_size,
                              hipStream_t stream) {
    const float* x     = (const float*)d_in[0];
    const float* w_row = (const float*)d_in[1];
    const float* b_row = (const float*)d_in[2];
    const float* w_col = (const float*)d_in[3];
    const float* b_col = (const float*)d_in[4];
    const float* g1    = (const float*)d_in[5];
    const float* be1   = (const float*)d_in[6];
    const float* g2    = (const float*)d_in[7];
    const float* be2   = (const float*)d_in[8];
    float* out = (float*)d_out;

    // ws: qkv 24MB | ao 8MB | o1b 8MB | xb 8MB | wrb/wcb 96KB+96KB | stats 256KB
    char* base = (char*)d_ws;
    u16*    qkvb  = (u16*)base;                                   base += (size_t)384 * SL * 2;
    u16*    ao16  = (u16*)base;                                   base += (size_t)128 * SL * 2;
    u16*    o1b   = (u16*)base;                                   base += (size_t)128 * SL * 2;
    u16*    xb    = (u16*)base;                                   base += (size_t)128 * SL * 2;
    u16*    wrb   = (u16*)base;                                   base += (size_t)384 * 128 * 2;
    u16*    wcb   = (u16*)base;                                   base += (size_t)384 * 128 * 2;
    float2* stats = (float2*)base;

    cast_kernel<<<2096, 256, 0, stream>>>(x, w_row, w_col, xb, wrb, wcb);
    qkv_mfma<<<1536, 256, 0, stream>>>(xb, wrb, b_row, qkvb);
    attn_kernel<256><<<2048, 256, 0, stream>>>(qkvb, ao16);
    stats_kernel<float><<<256, 128, 0, stream>>>(x, ao16, stats);
    apply_kernel<256, float, u16><<<1024, 256, 0, stream>>>(x, ao16, stats, g1, be1, o1b);
    qkv_mfma<<<1536, 256, 0, stream>>>(o1b, wcb, b_col, qkvb);
    attn_kernel<128><<<2048, 256, 0, stream>>>(qkvb, ao16);
    stats_kernel<u16><<<256, 128, 0, stream>>>(o1b, ao16, stats);
    apply_kernel<128, u16, float><<<1024, 256, 0, stream>>>(o1b, ao16, stats, g2, be2, out);
}